// Round 4
// baseline (203.395 us; speedup 1.0000x reference)
//
#include <hip/hip_runtime.h>
#include <math.h>

#define NF   39
#define NB   16384
#define NVOC 10000

typedef unsigned short u16;
typedef unsigned int   u32;
typedef float f32x4 __attribute__((ext_vector_type(4)));
typedef float f32x2 __attribute__((ext_vector_type(2)));
typedef short s16x8 __attribute__((ext_vector_type(8)));
typedef unsigned int u32x2 __attribute__((ext_vector_type(2)));

// ---- d_ws layout (u16 units) ----
// [0, E3_U16): E3 activations, fragment tiles: (st, f) -> 512 u16
// [E3_U16 ...): weights as 512-u16 fragment tiles:
//   per layer l (3 layers) at l*3072:
//     [0,1024)    A-frag of G^T (2 tiles), G = log2e * wq.wk^T   (Q/K fused)
//     [1024,2048) wv B-frag (2 tiles)
//     [2048,3072) wr A-frag (2 tiles)
//   W1 at 9216: (ks*8+nt), ks<39, nt<8 = 159744
//   W2 at 168960: (ks*4+nt), ks<4, nt<4 = 8192
//   W3 at 177152: (ks*2+nt), ks<2, nt<2 = 2048
#define E3_U16   20447232u
#define WOFF_W1  9216u
#define NSWZ     179200

__device__ __forceinline__ u32 bfadj(float x){
    u32 u = __float_as_uint(x);
    return u + 0x7fffu + ((u >> 16) & 1u);
}
__device__ __forceinline__ u32 pk2(float a, float b){
#if __has_builtin(__builtin_amdgcn_cvt_pk_bf16_f32)
    auto t = __builtin_amdgcn_cvt_pk_bf16_f32(a, b);
    u32 r; __builtin_memcpy(&r, &t, 4); return r;
#else
    return __builtin_amdgcn_perm(bfadj(a), bfadj(b), 0x03020706u);
#endif
}
__device__ __forceinline__ u16 f2bf(float f){ return (u16)(bfadj(f) >> 16); }

__device__ __forceinline__ float fexp2(float x){
#if __has_builtin(__builtin_amdgcn_exp2f)
    return __builtin_amdgcn_exp2f(x);
#else
    return exp2f(x);
#endif
}
__device__ __forceinline__ float frcp(float x){
#if __has_builtin(__builtin_amdgcn_rcpf)
    return __builtin_amdgcn_rcpf(x);
#else
    return 1.f / x;
#endif
}

__device__ __forceinline__ void wave_sync(){
    asm volatile("s_waitcnt lgkmcnt(0)" ::: "memory");
}
__device__ __forceinline__ f32x4 mfma16(s16x8 a, s16x8 b, f32x4 c){
    return __builtin_amdgcn_mfma_f32_16x16x32_bf16(a, b, c, 0, 0, 0);
}
__device__ __forceinline__ void store4(u16* p, f32x4 v){
    *(uint2*)p = make_uint2(pk2(v[0], v[1]), pk2(v[2], v[3]));
}

// ---- packed f32 (VOP3P dual-issue pairs) ----
__device__ __forceinline__ f32x2 pkadd(f32x2 a, f32x2 b){
    f32x2 d; asm("v_pk_add_f32 %0, %1, %2" : "=v"(d) : "v"(a), "v"(b)); return d;
}
__device__ __forceinline__ f32x2 pkmul(f32x2 a, f32x2 b){
    f32x2 d; asm("v_pk_mul_f32 %0, %1, %2" : "=v"(d) : "v"(a), "v"(b)); return d;
}

// ---- in-register C-layout -> fragment-layout rebuild ----
__device__ __forceinline__ void swap32(u32 &a, u32 &b){
    asm("v_permlane32_swap_b32 %0, %1" : "+v"(a), "+v"(b));
}
__device__ __forceinline__ void swap16(u32 &a, u32 &b){
    asm("v_permlane16_swap_b32 %0, %1" : "+v"(a), "+v"(b));
}
__device__ __forceinline__ s16x8 fragPack(u32 a0, u32 a1, u32 b0, u32 b1){
    swap32(a0, b0); swap16(a0, b0);   // a0 = w0, b0 = w2
    swap32(a1, b1); swap16(a1, b1);   // a1 = w1, b1 = w3
    union { u32 w[4]; s16x8 v; } u;
    u.w[0] = a0; u.w[1] = a1; u.w[2] = b0; u.w[3] = b1;
    return u.v;
}
// A = C tile holding frag k-rows 0-15, B = k-rows 16-31.
__device__ __forceinline__ s16x8 fragCC(f32x4 A, f32x4 B){
    return fragPack(pk2(A[0],A[1]), pk2(A[2],A[3]), pk2(B[0],B[1]), pk2(B[2],B[3]));
}
// B half known zero
__device__ __forceinline__ s16x8 fragC0(f32x4 A){
    return fragPack(pk2(A[0],A[1]), pk2(A[2],A[3]), 0u, 0u);
}
// scaled variants: multiply by iv (packed pair) before conversion
__device__ __forceinline__ s16x8 fragCCn(f32x4 A, f32x4 B, f32x2 iv){
    f32x2 a01 = pkmul(__builtin_shufflevector(A, A, 0, 1), iv);
    f32x2 a23 = pkmul(__builtin_shufflevector(A, A, 2, 3), iv);
    f32x2 b01 = pkmul(__builtin_shufflevector(B, B, 0, 1), iv);
    f32x2 b23 = pkmul(__builtin_shufflevector(B, B, 2, 3), iv);
    return fragPack(pk2(a01.x,a01.y), pk2(a23.x,a23.y),
                    pk2(b01.x,b01.y), pk2(b23.x,b23.y));
}
__device__ __forceinline__ s16x8 fragC0n(f32x4 A, f32x2 iv){
    f32x2 a01 = pkmul(__builtin_shufflevector(A, A, 0, 1), iv);
    f32x2 a23 = pkmul(__builtin_shufflevector(A, A, 2, 3), iv);
    return fragPack(pk2(a01.x,a01.y), pk2(a23.x,a23.y), 0u, 0u);
}
// lane-xor reductions via permlane
__device__ __forceinline__ float xadd16(float t){
    u32 a = __float_as_uint(t), b = a;
    swap16(a, b);
    return __uint_as_float(a) + __uint_as_float(b);
}
__device__ __forceinline__ float xadd32(float t){
    u32 a = __float_as_uint(t), b = a;
    swap32(a, b);
    return __uint_as_float(a) + __uint_as_float(b);
}

// ================= K0: weight pre-swizzle (+ Q/K fusion: G = log2e*wq.wk^T) ====
__global__ void __launch_bounds__(256) swz_kernel(
    const float* __restrict__ wq0, const float* __restrict__ wk0,
    const float* __restrict__ wv0, const float* __restrict__ wr0,
    const float* __restrict__ wq1, const float* __restrict__ wk1,
    const float* __restrict__ wv1, const float* __restrict__ wr1,
    const float* __restrict__ wq2, const float* __restrict__ wk2,
    const float* __restrict__ wv2, const float* __restrict__ wr2,
    const float* __restrict__ w1, const float* __restrict__ w2,
    const float* __restrict__ w3, u16* __restrict__ ws)
{
    int gid = (int)blockIdx.x*256 + (int)threadIdx.x;
    if (gid >= NSWZ) return;
    int w    = gid & 511;
    int lane = w >> 3, j = w & 7;
    int n    = lane & 15, quad = lane >> 4;
    int kin  = quad*8 + j;
    float val;
    if (gid < 9216){
        int l = gid / 3072;
        int rr = gid - l*3072;
        int kind = rr >> 10;          // 0=G, 1=wv, 2=wr
        int a    = (rr >> 9) & 1;     // tile index
        int din  = l ? 32 : 16;
        const float *WQ, *WK, *WV, *WR;
        if (l == 0){ WQ=wq0; WK=wk0; WV=wv0; WR=wr0; }
        else if (l == 1){ WQ=wq1; WK=wk1; WV=wv1; WR=wr1; }
        else { WQ=wq2; WK=wk2; WV=wv2; WR=wr2; }
        if (kind == 0){
            // A-frag of G^T: element (m=a*16+n, k=kin); G = wq.wk^T, log2e folded
            int dp = a*16 + n;
            float s = 0.f;
            if (dp < din && kin < din){
                float acc = 0.f;
                for (int e = 0; e < 32; ++e)
                    acc += WQ[kin*32 + e] * WK[dp*32 + e];
                s = acc * 1.44269504f;
            }
            val = s;
        } else {
            const float* W = (kind == 1) ? WV : WR;
            val = (kin < din) ? W[kin*32 + a*16 + n] : 0.f;
        }
    } else if (gid < 9216 + 159744){
        int tt = (gid - 9216) >> 9;
        int ks = tt >> 3, nt = tt & 7;
        val = w1[(ks*32 + kin)*128 + nt*16 + n];
    } else if (gid < 9216 + 159744 + 8192){
        int tt = (gid - (9216+159744)) >> 9;
        int ks = tt >> 2, nt = tt & 3;
        val = w2[(ks*32 + kin)*64 + nt*16 + n];
    } else {
        int tt = (gid - (9216+159744+8192)) >> 9;
        int ks = tt >> 1, nt = tt & 1;
        val = w3[(ks*32 + kin)*32 + nt*16 + n];
    }
    ws[E3_U16 + gid] = f2bf(val);
}

// ================= K1: fused attention — fully in-register ====================
// Per wave: 1 sample. LDS only stages the embedding gather (3 tiles = 1536 u16).
// Softmax normalization folded into P conversion (pk_mul); wr residual folded
// into the O MFMA C-operand; mask via zeroed inv/R on lanes nl>=7 (nt==2).
__global__ void __launch_bounds__(256, 4) attn_kernel(
    const int* __restrict__ x, const float* __restrict__ emb,
    u16* __restrict__ ws)
{
    __shared__ __align__(16) u16 lds[4*1536];
    const int tid  = (int)threadIdx.x;
    const int wid  = tid >> 6, lane = tid & 63;
    const int h    = lane >> 4, nl = lane & 15;
    const int r    = (int)blockIdx.x*4 + wid;

    u16* eBuf = lds + wid*1536;
    const u16* wmat = ws + E3_U16;
    const f32x4 z = {0.f, 0.f, 0.f, 0.f};

    // S^T C-init: pad rows g>=39 (mtg=2 tile: g = 32 + 4h + reg)
    f32x4 ci;
#pragma unroll
    for (int reg = 0; reg < 4; ++reg)
        ci[reg] = (h*4 + reg >= 7) ? -1e30f : 0.f;

    // ---- embedding gather -> E A-frag (k rows 16-31 zero-padded) ----
    if (lane < 48){
        int f = lane, mt = f >> 4, fl = f & 15;
        u16* row = eBuf + mt*512 + fl*8;
        if (f < NF){
            const float4* ep = (const float4*)(emb + ((size_t)(x[r*NF + f] + f*NVOC))*16);
            float4 e0 = ep[0], e1 = ep[1], e2 = ep[2], e3 = ep[3];
            *(uint4*)(row)       = make_uint4(pk2(e0.x,e0.y), pk2(e0.z,e0.w),
                                              pk2(e1.x,e1.y), pk2(e1.z,e1.w));
            *(uint4*)(row + 128) = make_uint4(pk2(e2.x,e2.y), pk2(e2.z,e2.w),
                                              pk2(e3.x,e3.y), pk2(e3.z,e3.w));
        } else {
            *(uint4*)(row)       = make_uint4(0,0,0,0);
            *(uint4*)(row + 128) = make_uint4(0,0,0,0);
        }
        *(uint4*)(row + 256) = make_uint4(0,0,0,0);
        *(uint4*)(row + 384) = make_uint4(0,0,0,0);
    }
    wave_sync();
    s16x8 bE[3];
#pragma unroll
    for (int nt = 0; nt < 3; ++nt)
        bE[nt] = *(const s16x8*)(eBuf + nt*512 + lane*8);

#pragma unroll 1
    for (int L = 0; L < 3; ++L){
        const u16* wL = wmat + L*3072;

        // ---- T^T = G^T E^T  (Q/K fused) -> bT fragments in-register ----
        s16x8 bT[3];
        {
            s16x8 g0 = *(const s16x8*)(wL +       lane*8);
            s16x8 g1 = *(const s16x8*)(wL + 512 + lane*8);
#pragma unroll
            for (int nt = 0; nt < 3; ++nt)
                bT[nt] = fragCC(mfma16(g0, bE[nt], z), mfma16(g1, bE[nt], z));
        }
        // ---- V -> aV fragments in-register (k rows 48-63 zero) ----
        s16x8 aV[2][2];
        {
            s16x8 v0 = *(const s16x8*)(wL + 1024 + lane*8);
            s16x8 v1 = *(const s16x8*)(wL + 1536 + lane*8);
#pragma unroll
            for (int emt = 0; emt < 2; ++emt){
                s16x8 vb = emt ? v1 : v0;
                f32x4 c0 = mfma16(bE[0], vb, z);
                f32x4 c1 = mfma16(bE[1], vb, z);
                f32x4 c2 = mfma16(bE[2], vb, z);
                aV[0][emt] = fragCC(c0, c1);
                aV[1][emt] = fragC0(c2);
            }
        }
        // ---- S^T = E T^T (9 MFMAs); A-operand is bE itself; logits in log2 ----
        f32x4 S[3][3];
#pragma unroll
        for (int mtg = 0; mtg < 3; ++mtg)
#pragma unroll
        for (int nt = 0; nt < 3; ++nt)
            S[mtg][nt] = mfma16(bE[mtg], bT[nt], (mtg == 2) ? ci : z);

        // ---- exp2 + rowsum (pk_add pairs + permlane reduce) ----
        float inv[3];
#pragma unroll
        for (int nt = 0; nt < 3; ++nt){
            f32x2 acc2 = {0.f, 0.f};
#pragma unroll
            for (int mtg = 0; mtg < 3; ++mtg){
#pragma unroll
                for (int reg = 0; reg < 4; ++reg)
                    S[mtg][nt][reg] = fexp2(S[mtg][nt][reg]);
                acc2 = pkadd(acc2, __builtin_shufflevector(S[mtg][nt], S[mtg][nt], 0, 1));
                acc2 = pkadd(acc2, __builtin_shufflevector(S[mtg][nt], S[mtg][nt], 2, 3));
            }
            inv[nt] = frcp(xadd32(xadd16(acc2.x + acc2.y)));
        }
        inv[2] = (nl < 7) ? inv[2] : 0.f;   // mask cols f>=39

        // ---- R^T in regs (C layout of O^T), masked cols zeroed ----
        f32x4 R[2][3];
        {
            s16x8 r0 = *(const s16x8*)(wL + 2048 + lane*8);
            s16x8 r1 = *(const s16x8*)(wL + 2560 + lane*8);
#pragma unroll
            for (int nt = 0; nt < 3; ++nt){
                R[0][nt] = mfma16(r0, bE[nt], z);
                R[1][nt] = mfma16(r1, bE[nt], z);
            }
        }
        if (nl >= 7){ R[0][2] = z; R[1][2] = z; }

        // ---- P fragments (normalized in conversion) + O^T (C = R) ----
        if (L < 2){
#pragma unroll
            for (int nt = 0; nt < 3; ++nt){
                f32x2 iv = {inv[nt], inv[nt]};
                s16x8 p0 = fragCCn(S[0][nt], S[1][nt], iv);  // k = g 0..31
                s16x8 p1 = fragC0n(S[2][nt], iv);            // k = g 32..47
                f32x4 oc[2];
#pragma unroll
                for (int emt = 0; emt < 2; ++emt){
                    f32x4 o = mfma16(aV[1][emt], p1,
                              mfma16(aV[0][emt], p0, R[emt][nt]));
#pragma unroll
                    for (int reg = 0; reg < 4; ++reg)
                        o[reg] = fmaxf(o[reg], 0.f);
                    oc[emt] = o;
                }
                bE[nt] = fragCC(oc[0], oc[1]);               // next-layer E fragment
            }
        } else {
            int st = r >> 4, sm = r & 15;
            u32 base = (u32)(st*39)*512u + (u32)(sm*8 + (h>>1)*128 + (h&1)*4);
#pragma unroll
            for (int nt = 0; nt < 3; ++nt){
                f32x2 iv = {inv[nt], inv[nt]};
                s16x8 p0 = fragCCn(S[0][nt], S[1][nt], iv);
                s16x8 p1 = fragC0n(S[2][nt], iv);
                int f = nt*16 + nl;
#pragma unroll
                for (int emt = 0; emt < 2; ++emt){
                    f32x4 o = mfma16(aV[1][emt], p1,
                              mfma16(aV[0][emt], p0, R[emt][nt]));
#pragma unroll
                    for (int reg = 0; reg < 4; ++reg)
                        o[reg] = fmaxf(o[reg], 0.f);
                    if (f < NF)
                        *(uint2*)(ws + base + (u32)f*512u + emt*256) =
                            make_uint2(pk2(o[0], o[1]), pk2(o[2], o[3]));
                }
            }
        }
    }
}

// ================= K2: MLP v2 — 64 samples/block, wave-private sample tile ====
// Each wave owns one 16-sample tile and runs the FULL K=39 GEMM1 loop (no
// K-split, no cross-wave reduction). 256 blocks (1/CU): W1 fragment traffic
// drops 327 MB -> 82 MB and stays L2-resident; h1/h2 are wave-private LDS
// (lgkmcnt-only sync, no __syncthreads).
__global__ void __launch_bounds__(256, 4) mlp_kernel(
    const float* __restrict__ b1, const float* __restrict__ b2,
    const float* __restrict__ b3, const float* __restrict__ w4,
    const float* __restrict__ b4, const u16* __restrict__ ws,
    float* __restrict__ out)
{
    __shared__ __align__(16) u16 h1t[4*2048];
    __shared__ __align__(16) u16 h2t[4*1024];
    const int tid = (int)threadIdx.x;
    const int w   = tid >> 6, lane = tid & 63;
    const int h   = lane >> 4, nl = lane & 15;
    const int st  = (int)blockIdx.x*4 + w;     // wave-private sample tile
    const int A_off = nl*8 + (h>>1)*128 + (h&1)*4;

    u16* h1w = h1t + w*2048;
    u16* h2w = h2t + w*1024;
    const u16* w1b = ws + E3_U16 + WOFF_W1;
    const u16* w2b = w1b + 159744u;
    const u16* w3b = w2b + 8192u;
    const f32x4 z = {0.f,0.f,0.f,0.f};

    // ---- GEMM1: h1^T = w1^T x e3^T, full K per wave ----
    f32x4 acc[8];
#pragma unroll
    for (int nt = 0; nt < 8; ++nt) acc[nt] = z;
#pragma unroll 2
    for (int ks = 0; ks < 39; ++ks){
        s16x8 aE = __builtin_nontemporal_load(
            (const s16x8*)(ws + (u32)(st*39 + ks)*512u + lane*8));
#pragma unroll
        for (int nt = 0; nt < 8; ++nt){
            s16x8 aW = *(const s16x8*)(w1b + (ks*8 + nt)*512 + lane*8);
            acc[nt] = mfma16(aW, aE, acc[nt]);
        }
    }
#pragma unroll
    for (int nt = 0; nt < 8; ++nt){
        float4 bv = *(const float4*)(b1 + nt*16 + h*4);
        f32x4 v;
        v[0] = fmaxf(acc[nt][0] + bv.x, 0.f);
        v[1] = fmaxf(acc[nt][1] + bv.y, 0.f);
        v[2] = fmaxf(acc[nt][2] + bv.z, 0.f);
        v[3] = fmaxf(acc[nt][3] + bv.w, 0.f);
        store4(h1w + nt*256 + A_off, v);
    }
    wave_sync();

    // ---- GEMM2: h2^T = w2^T x h1^T (per wave, all 4 nt) ----
    {
        f32x4 a2[4];
#pragma unroll
        for (int nt = 0; nt < 4; ++nt) a2[nt] = z;
#pragma unroll
        for (int ks = 0; ks < 4; ++ks){
            s16x8 bH = *(const s16x8*)(h1w + ks*512 + lane*8);
#pragma unroll
            for (int nt = 0; nt < 4; ++nt){
                s16x8 aW = *(const s16x8*)(w2b + (ks*4 + nt)*512 + lane*8);
                a2[nt] = mfma16(aW, bH, a2[nt]);
            }
        }
#pragma unroll
        for (int nt = 0; nt < 4; ++nt){
            float4 bv = *(const float4*)(b2 + nt*16 + h*4);
            f32x4 v;
            v[0] = fmaxf(a2[nt][0] + bv.x, 0.f);
            v[1] = fmaxf(a2[nt][1] + bv.y, 0.f);
            v[2] = fmaxf(a2[nt][2] + bv.z, 0.f);
            v[3] = fmaxf(a2[nt][3] + bv.w, 0.f);
            store4(h2w + (nt>>1)*512 + (nt&1)*256 + A_off, v);
        }
    }
    wave_sync();

    // ---- GEMM3 + w4 dot (per wave) ----
    {
        float t = 0.f;
#pragma unroll
        for (int nt = 0; nt < 2; ++nt){
            f32x4 a3 = z;
#pragma unroll
            for (int ks = 0; ks < 2; ++ks){
                s16x8 aW = *(const s16x8*)(w3b + (ks*2 + nt)*512 + lane*8);
                s16x8 bH = *(const s16x8*)(h2w + ks*512 + lane*8);
                a3 = mfma16(aW, bH, a3);
            }
            float4 b3v = *(const float4*)(b3 + nt*16 + h*4);
            float4 w4v = *(const float4*)(w4 + nt*16 + h*4);
            t += fmaxf(a3[0] + b3v.x, 0.f)*w4v.x
               + fmaxf(a3[1] + b3v.y, 0.f)*w4v.y
               + fmaxf(a3[2] + b3v.z, 0.f)*w4v.z
               + fmaxf(a3[3] + b3v.w, 0.f)*w4v.w;
        }
        t += __shfl_xor(t, 16, 64);
        t += __shfl_xor(t, 32, 64);
        if (h == 0){
            float zz = t + b4[0];
            out[st*16 + nl] = 1.f/(1.f + __expf(-zz));
        }
    }
}

extern "C" void kernel_launch(void* const* d_in, const int* in_sizes, int n_in,
                              void* d_out, int out_size, void* d_ws, size_t ws_size,
                              hipStream_t stream)
{
    (void)in_sizes; (void)n_in; (void)ws_size; (void)out_size;
    const int*   x   = (const int*)d_in[0];
    const float* emb = (const float*)d_in[1];
    u16* ws = (u16*)d_ws;

    swz_kernel<<<(NSWZ+255)/256, 256, 0, stream>>>(
        (const float*)d_in[2],  (const float*)d_in[3],  (const float*)d_in[4],  (const float*)d_in[5],
        (const float*)d_in[6],  (const float*)d_in[7],  (const float*)d_in[8],  (const float*)d_in[9],
        (const float*)d_in[10], (const float*)d_in[11], (const float*)d_in[12], (const float*)d_in[13],
        (const float*)d_in[14], (const float*)d_in[16], (const float*)d_in[18], ws);

    attn_kernel<<<NB/4, 256, 0, stream>>>(x, emb, ws);

    mlp_kernel<<<NB/64, 256, 0, stream>>>(
        (const float*)d_in[15], (const float*)d_in[17], (const float*)d_in[19],
        (const float*)d_in[20], (const float*)d_in[21], ws, (float*)d_out);
}

// Round 6
// 174.539 us; speedup vs baseline: 1.1653x; 1.1653x over previous
//
#include <hip/hip_runtime.h>
#include <math.h>

#define NF   39
#define NB   16384
#define NVOC 10000

typedef unsigned short u16;
typedef unsigned int   u32;
typedef float f32x4 __attribute__((ext_vector_type(4)));
typedef float f32x2 __attribute__((ext_vector_type(2)));
typedef short s16x8 __attribute__((ext_vector_type(8)));
typedef __bf16 bf16x2 __attribute__((ext_vector_type(2)));

// ---- d_ws layout (u16 units) ----
// [0, E3_U16): E3 activations, fragment tiles: (st, f) -> 512 u16
// [E3_U16 ...): weights as 512-u16 fragment tiles:
//   per layer l (3 layers) at l*3072:
//     [0,1024)    A-frag of G^T (2 tiles), G = log2e * wq.wk^T   (Q/K fused)
//     [1024,2048) wv B-frag (2 tiles)
//     [2048,3072) wr A-frag (2 tiles)
//   W1 at 9216: (ks*8+nt), ks<39, nt<8 = 159744
//   W2 at 168960: (ks*4+nt), ks<4, nt<4 = 8192
//   W3 at 177152: (ks*2+nt), ks<2, nt<2 = 2048
#define E3_U16   20447232u
#define WOFF_W1  9216u
#define NSWZ     179200

__device__ __forceinline__ u32 bfadj(float x){
    u32 u = __float_as_uint(x);
    return u + 0x7fffu + ((u >> 16) & 1u);
}
// packed f32->bf16 via COMPILER casts: LLVM's gfx950 pattern fuses the two
// fptruncs into one v_cvt_pk_bf16_f32 (m240: "compiler handles it" — the
// hand-written asm variant caused the round-5 NaN; casts are semantics-safe).
__device__ __forceinline__ u32 pk2(float a, float b){
    bf16x2 t;
    t[0] = (__bf16)a;
    t[1] = (__bf16)b;
    u32 r; __builtin_memcpy(&r, &t, 4); return r;
}
__device__ __forceinline__ u16 f2bf(float f){ return (u16)(bfadj(f) >> 16); }

__device__ __forceinline__ float fexp2(float x){
#if __has_builtin(__builtin_amdgcn_exp2f)
    return __builtin_amdgcn_exp2f(x);
#else
    return exp2f(x);
#endif
}
__device__ __forceinline__ float frcp(float x){
#if __has_builtin(__builtin_amdgcn_rcpf)
    return __builtin_amdgcn_rcpf(x);
#else
    return 1.f / x;
#endif
}

__device__ __forceinline__ void wave_sync(){
    asm volatile("s_waitcnt lgkmcnt(0)" ::: "memory");
}
__device__ __forceinline__ f32x4 mfma16(s16x8 a, s16x8 b, f32x4 c){
    return __builtin_amdgcn_mfma_f32_16x16x32_bf16(a, b, c, 0, 0, 0);
}
__device__ __forceinline__ void store4(u16* p, f32x4 v){
    *(uint2*)p = make_uint2(pk2(v[0], v[1]), pk2(v[2], v[3]));
}

// ---- packed f32 (VOP3P dual-issue pairs) ----
__device__ __forceinline__ f32x2 pkadd(f32x2 a, f32x2 b){
    f32x2 d; asm("v_pk_add_f32 %0, %1, %2" : "=v"(d) : "v"(a), "v"(b)); return d;
}
__device__ __forceinline__ f32x2 pkmul(f32x2 a, f32x2 b){
    f32x2 d; asm("v_pk_mul_f32 %0, %1, %2" : "=v"(d) : "v"(a), "v"(b)); return d;
}

// ---- in-register C-layout -> fragment-layout rebuild ----
__device__ __forceinline__ void swap32(u32 &a, u32 &b){
    asm("v_permlane32_swap_b32 %0, %1" : "+v"(a), "+v"(b));
}
__device__ __forceinline__ void swap16(u32 &a, u32 &b){
    asm("v_permlane16_swap_b32 %0, %1" : "+v"(a), "+v"(b));
}
__device__ __forceinline__ s16x8 fragPack(u32 a0, u32 a1, u32 b0, u32 b1){
    swap32(a0, b0); swap16(a0, b0);   // a0 = w0, b0 = w2
    swap32(a1, b1); swap16(a1, b1);   // a1 = w1, b1 = w3
    union { u32 w[4]; s16x8 v; } u;
    u.w[0] = a0; u.w[1] = a1; u.w[2] = b0; u.w[3] = b1;
    return u.v;
}
// A = C tile holding frag k-rows 0-15, B = k-rows 16-31.
__device__ __forceinline__ s16x8 fragCC(f32x4 A, f32x4 B){
    return fragPack(pk2(A[0],A[1]), pk2(A[2],A[3]), pk2(B[0],B[1]), pk2(B[2],B[3]));
}
// B half known zero
__device__ __forceinline__ s16x8 fragC0(f32x4 A){
    return fragPack(pk2(A[0],A[1]), pk2(A[2],A[3]), 0u, 0u);
}
// scaled variants: multiply by iv (packed pair) before conversion
__device__ __forceinline__ s16x8 fragCCn(f32x4 A, f32x4 B, f32x2 iv){
    f32x2 a01 = pkmul(__builtin_shufflevector(A, A, 0, 1), iv);
    f32x2 a23 = pkmul(__builtin_shufflevector(A, A, 2, 3), iv);
    f32x2 b01 = pkmul(__builtin_shufflevector(B, B, 0, 1), iv);
    f32x2 b23 = pkmul(__builtin_shufflevector(B, B, 2, 3), iv);
    return fragPack(pk2(a01.x,a01.y), pk2(a23.x,a23.y),
                    pk2(b01.x,b01.y), pk2(b23.x,b23.y));
}
__device__ __forceinline__ s16x8 fragC0n(f32x4 A, f32x2 iv){
    f32x2 a01 = pkmul(__builtin_shufflevector(A, A, 0, 1), iv);
    f32x2 a23 = pkmul(__builtin_shufflevector(A, A, 2, 3), iv);
    return fragPack(pk2(a01.x,a01.y), pk2(a23.x,a23.y), 0u, 0u);
}
// lane-xor reductions via permlane
__device__ __forceinline__ float xadd16(float t){
    u32 a = __float_as_uint(t), b = a;
    swap16(a, b);
    return __uint_as_float(a) + __uint_as_float(b);
}
__device__ __forceinline__ float xadd32(float t){
    u32 a = __float_as_uint(t), b = a;
    swap32(a, b);
    return __uint_as_float(a) + __uint_as_float(b);
}

// ================= K0: weight pre-swizzle (+ Q/K fusion: G = log2e*wq.wk^T) ====
__global__ void __launch_bounds__(256) swz_kernel(
    const float* __restrict__ wq0, const float* __restrict__ wk0,
    const float* __restrict__ wv0, const float* __restrict__ wr0,
    const float* __restrict__ wq1, const float* __restrict__ wk1,
    const float* __restrict__ wv1, const float* __restrict__ wr1,
    const float* __restrict__ wq2, const float* __restrict__ wk2,
    const float* __restrict__ wv2, const float* __restrict__ wr2,
    const float* __restrict__ w1, const float* __restrict__ w2,
    const float* __restrict__ w3, u16* __restrict__ ws)
{
    int gid = (int)blockIdx.x*256 + (int)threadIdx.x;
    if (gid >= NSWZ) return;
    int w    = gid & 511;
    int lane = w >> 3, j = w & 7;
    int n    = lane & 15, quad = lane >> 4;
    int kin  = quad*8 + j;
    float val;
    if (gid < 9216){
        int l = gid / 3072;
        int rr = gid - l*3072;
        int kind = rr >> 10;          // 0=G, 1=wv, 2=wr
        int a    = (rr >> 9) & 1;     // tile index
        int din  = l ? 32 : 16;
        const float *WQ, *WK, *WV, *WR;
        if (l == 0){ WQ=wq0; WK=wk0; WV=wv0; WR=wr0; }
        else if (l == 1){ WQ=wq1; WK=wk1; WV=wv1; WR=wr1; }
        else { WQ=wq2; WK=wk2; WV=wv2; WR=wr2; }
        if (kind == 0){
            // A-frag of G^T: element (m=a*16+n, k=kin); G = wq.wk^T, log2e folded
            int dp = a*16 + n;
            float s = 0.f;
            if (dp < din && kin < din){
                float acc = 0.f;
                for (int e = 0; e < 32; ++e)
                    acc += WQ[kin*32 + e] * WK[dp*32 + e];
                s = acc * 1.44269504f;
            }
            val = s;
        } else {
            const float* W = (kind == 1) ? WV : WR;
            val = (kin < din) ? W[kin*32 + a*16 + n] : 0.f;
        }
    } else if (gid < 9216 + 159744){
        int tt = (gid - 9216) >> 9;
        int ks = tt >> 3, nt = tt & 7;
        val = w1[(ks*32 + kin)*128 + nt*16 + n];
    } else if (gid < 9216 + 159744 + 8192){
        int tt = (gid - (9216+159744)) >> 9;
        int ks = tt >> 2, nt = tt & 3;
        val = w2[(ks*32 + kin)*64 + nt*16 + n];
    } else {
        int tt = (gid - (9216+159744+8192)) >> 9;
        int ks = tt >> 1, nt = tt & 1;
        val = w3[(ks*32 + kin)*32 + nt*16 + n];
    }
    ws[E3_U16 + gid] = f2bf(val);
}

// ================= K1: fused attention — fully in-register ====================
// Per wave: 1 sample. LDS only stages the embedding gather (3 tiles = 1536 u16).
// Softmax normalization folded into P conversion (pk_mul); wr residual folded
// into the O MFMA C-operand; mask via zeroed inv/R on lanes nl>=7 (nt==2).
__global__ void __launch_bounds__(256, 4) attn_kernel(
    const int* __restrict__ x, const float* __restrict__ emb,
    u16* __restrict__ ws)
{
    __shared__ __align__(16) u16 lds[4*1536];
    const int tid  = (int)threadIdx.x;
    const int wid  = tid >> 6, lane = tid & 63;
    const int h    = lane >> 4, nl = lane & 15;
    const int r    = (int)blockIdx.x*4 + wid;

    u16* eBuf = lds + wid*1536;
    const u16* wmat = ws + E3_U16;
    const f32x4 z = {0.f, 0.f, 0.f, 0.f};

    // S^T C-init: pad rows g>=39 (mtg=2 tile: g = 32 + 4h + reg)
    f32x4 ci;
#pragma unroll
    for (int reg = 0; reg < 4; ++reg)
        ci[reg] = (h*4 + reg >= 7) ? -1e30f : 0.f;

    // ---- embedding gather -> E A-frag (k rows 16-31 zero-padded) ----
    if (lane < 48){
        int f = lane, mt = f >> 4, fl = f & 15;
        u16* row = eBuf + mt*512 + fl*8;
        if (f < NF){
            const float4* ep = (const float4*)(emb + ((size_t)(x[r*NF + f] + f*NVOC))*16);
            float4 e0 = ep[0], e1 = ep[1], e2 = ep[2], e3 = ep[3];
            *(uint4*)(row)       = make_uint4(pk2(e0.x,e0.y), pk2(e0.z,e0.w),
                                              pk2(e1.x,e1.y), pk2(e1.z,e1.w));
            *(uint4*)(row + 128) = make_uint4(pk2(e2.x,e2.y), pk2(e2.z,e2.w),
                                              pk2(e3.x,e3.y), pk2(e3.z,e3.w));
        } else {
            *(uint4*)(row)       = make_uint4(0,0,0,0);
            *(uint4*)(row + 128) = make_uint4(0,0,0,0);
        }
        *(uint4*)(row + 256) = make_uint4(0,0,0,0);
        *(uint4*)(row + 384) = make_uint4(0,0,0,0);
    }
    wave_sync();
    s16x8 bE[3];
#pragma unroll
    for (int nt = 0; nt < 3; ++nt)
        bE[nt] = *(const s16x8*)(eBuf + nt*512 + lane*8);

#pragma unroll 1
    for (int L = 0; L < 3; ++L){
        const u16* wL = wmat + L*3072;

        // ---- T^T = G^T E^T  (Q/K fused) -> bT fragments in-register ----
        s16x8 bT[3];
        {
            s16x8 g0 = *(const s16x8*)(wL +       lane*8);
            s16x8 g1 = *(const s16x8*)(wL + 512 + lane*8);
#pragma unroll
            for (int nt = 0; nt < 3; ++nt)
                bT[nt] = fragCC(mfma16(g0, bE[nt], z), mfma16(g1, bE[nt], z));
        }
        // ---- V -> aV fragments in-register (k rows 48-63 zero) ----
        s16x8 aV[2][2];
        {
            s16x8 v0 = *(const s16x8*)(wL + 1024 + lane*8);
            s16x8 v1 = *(const s16x8*)(wL + 1536 + lane*8);
#pragma unroll
            for (int emt = 0; emt < 2; ++emt){
                s16x8 vb = emt ? v1 : v0;
                f32x4 c0 = mfma16(bE[0], vb, z);
                f32x4 c1 = mfma16(bE[1], vb, z);
                f32x4 c2 = mfma16(bE[2], vb, z);
                aV[0][emt] = fragCC(c0, c1);
                aV[1][emt] = fragC0(c2);
            }
        }
        // ---- S^T = E T^T (9 MFMAs); A-operand is bE itself; logits in log2 ----
        f32x4 S[3][3];
#pragma unroll
        for (int mtg = 0; mtg < 3; ++mtg)
#pragma unroll
        for (int nt = 0; nt < 3; ++nt)
            S[mtg][nt] = mfma16(bE[mtg], bT[nt], (mtg == 2) ? ci : z);

        // ---- exp2 + rowsum (pk_add pairs + permlane reduce) ----
        float inv[3];
#pragma unroll
        for (int nt = 0; nt < 3; ++nt){
            f32x2 acc2 = {0.f, 0.f};
#pragma unroll
            for (int mtg = 0; mtg < 3; ++mtg){
#pragma unroll
                for (int reg = 0; reg < 4; ++reg)
                    S[mtg][nt][reg] = fexp2(S[mtg][nt][reg]);
                acc2 = pkadd(acc2, __builtin_shufflevector(S[mtg][nt], S[mtg][nt], 0, 1));
                acc2 = pkadd(acc2, __builtin_shufflevector(S[mtg][nt], S[mtg][nt], 2, 3));
            }
            inv[nt] = frcp(xadd32(xadd16(acc2.x + acc2.y)));
        }
        inv[2] = (nl < 7) ? inv[2] : 0.f;   // mask cols f>=39

        // ---- R^T in regs (C layout of O^T), masked cols zeroed ----
        f32x4 R[2][3];
        {
            s16x8 r0 = *(const s16x8*)(wL + 2048 + lane*8);
            s16x8 r1 = *(const s16x8*)(wL + 2560 + lane*8);
#pragma unroll
            for (int nt = 0; nt < 3; ++nt){
                R[0][nt] = mfma16(r0, bE[nt], z);
                R[1][nt] = mfma16(r1, bE[nt], z);
            }
        }
        if (nl >= 7){ R[0][2] = z; R[1][2] = z; }

        // ---- P fragments (normalized in conversion) + O^T (C = R) ----
        if (L < 2){
#pragma unroll
            for (int nt = 0; nt < 3; ++nt){
                f32x2 iv = {inv[nt], inv[nt]};
                s16x8 p0 = fragCCn(S[0][nt], S[1][nt], iv);  // k = g 0..31
                s16x8 p1 = fragC0n(S[2][nt], iv);            // k = g 32..47
                f32x4 oc[2];
#pragma unroll
                for (int emt = 0; emt < 2; ++emt){
                    f32x4 o = mfma16(aV[1][emt], p1,
                              mfma16(aV[0][emt], p0, R[emt][nt]));
#pragma unroll
                    for (int reg = 0; reg < 4; ++reg)
                        o[reg] = fmaxf(o[reg], 0.f);
                    oc[emt] = o;
                }
                bE[nt] = fragCC(oc[0], oc[1]);               // next-layer E fragment
            }
        } else {
            int st = r >> 4, sm = r & 15;
            u32 base = (u32)(st*39)*512u + (u32)(sm*8 + (h>>1)*128 + (h&1)*4);
#pragma unroll
            for (int nt = 0; nt < 3; ++nt){
                f32x2 iv = {inv[nt], inv[nt]};
                s16x8 p0 = fragCCn(S[0][nt], S[1][nt], iv);
                s16x8 p1 = fragC0n(S[2][nt], iv);
                int f = nt*16 + nl;
#pragma unroll
                for (int emt = 0; emt < 2; ++emt){
                    f32x4 o = mfma16(aV[1][emt], p1,
                              mfma16(aV[0][emt], p0, R[emt][nt]));
#pragma unroll
                    for (int reg = 0; reg < 4; ++reg)
                        o[reg] = fmaxf(o[reg], 0.f);
                    if (f < NF)
                        *(uint2*)(ws + base + (u32)f*512u + emt*256) =
                            make_uint2(pk2(o[0], o[1]), pk2(o[2], o[3]));
                }
            }
        }
    }
}

// ================= K2: MLP, 16 samples/block, K-split GEMM1 (round-1 v1) =====
__global__ void __launch_bounds__(256, 4) mlp_kernel(
    const float* __restrict__ b1, const float* __restrict__ b2,
    const float* __restrict__ b3, const float* __restrict__ w4,
    const float* __restrict__ b4, const u16* __restrict__ ws,
    float* __restrict__ out)
{
    __shared__ __align__(16) float red[8192];
    __shared__ __align__(16) u16 h1t[2048];
    __shared__ __align__(16) u16 h2t[1024];
    __shared__ float part[32];
    const int tid = (int)threadIdx.x;
    const int w   = tid >> 6, lane = tid & 63;
    const int h   = lane >> 4, nl = lane & 15;
    const int st  = (int)blockIdx.x;
    const int A_off = nl*8 + (h>>1)*128 + (h&1)*4;

    const u16* w1b = ws + E3_U16 + WOFF_W1;
    const u16* w2b = w1b + 159744u;
    const u16* w3b = w2b + 8192u;
    const f32x4 z = {0.f,0.f,0.f,0.f};

    // ---- GEMM1: h1^T = w1^T x e3^T, K split across 4 waves ----
    f32x4 acc[8];
#pragma unroll
    for (int nt = 0; nt < 8; ++nt) acc[nt] = z;
#pragma unroll 2
    for (int ks = w; ks < 39; ks += 4){
        s16x8 aE = *(const s16x8*)(ws + (u32)(st*39 + ks)*512u + lane*8);
#pragma unroll
        for (int nt = 0; nt < 8; ++nt){
            s16x8 aW = *(const s16x8*)(w1b + (ks*8 + nt)*512 + lane*8);
            acc[nt] = mfma16(aW, aE, acc[nt]);
        }
    }
#pragma unroll
    for (int nt = 0; nt < 8; ++nt)
        *(f32x4*)(red + (w*8 + nt)*256 + lane*4) = acc[nt];
    __syncthreads();

#pragma unroll
    for (int t = 0; t < 2; ++t){
        int ft = 2*w + t;
        f32x4 s = *(const f32x4*)(red + (0*8 + ft)*256 + lane*4);
#pragma unroll
        for (int p = 1; p < 4; ++p){
            f32x4 q = *(const f32x4*)(red + (p*8 + ft)*256 + lane*4);
#pragma unroll
            for (int reg = 0; reg < 4; ++reg) s[reg] += q[reg];
        }
        float4 bv = *(const float4*)(b1 + ft*16 + h*4);
        f32x4 v;
        v[0] = fmaxf(s[0] + bv.x, 0.f);
        v[1] = fmaxf(s[1] + bv.y, 0.f);
        v[2] = fmaxf(s[2] + bv.z, 0.f);
        v[3] = fmaxf(s[3] + bv.w, 0.f);
        store4(h1t + ft*256 + A_off, v);
    }
    __syncthreads();

    // ---- GEMM2: h2^T = w2^T x h1^T ----
    {
        f32x4 a2 = z;
#pragma unroll
        for (int ks = 0; ks < 4; ++ks){
            s16x8 aW = *(const s16x8*)(w2b + (ks*4 + w)*512 + lane*8);
            s16x8 bH = *(const s16x8*)(h1t + ks*512 + lane*8);
            a2 = mfma16(aW, bH, a2);
        }
        float4 bv = *(const float4*)(b2 + w*16 + h*4);
        f32x4 v;
        v[0] = fmaxf(a2[0] + bv.x, 0.f);
        v[1] = fmaxf(a2[1] + bv.y, 0.f);
        v[2] = fmaxf(a2[2] + bv.z, 0.f);
        v[3] = fmaxf(a2[3] + bv.w, 0.f);
        store4(h2t + (w>>1)*512 + (w&1)*256 + A_off, v);
    }
    __syncthreads();

    // ---- GEMM3 (waves 0,1) + w4 dot ----
    if (w < 2){
        f32x4 a3 = z;
#pragma unroll
        for (int ks = 0; ks < 2; ++ks){
            s16x8 aW = *(const s16x8*)(w3b + (ks*2 + w)*512 + lane*8);
            s16x8 bH = *(const s16x8*)(h2t + ks*512 + lane*8);
            a3 = mfma16(aW, bH, a3);
        }
        float4 b3v = *(const float4*)(b3 + w*16 + h*4);
        float4 w4v = *(const float4*)(w4 + w*16 + h*4);
        float t = fmaxf(a3[0] + b3v.x, 0.f)*w4v.x
                + fmaxf(a3[1] + b3v.y, 0.f)*w4v.y
                + fmaxf(a3[2] + b3v.z, 0.f)*w4v.z
                + fmaxf(a3[3] + b3v.w, 0.f)*w4v.w;
        t += __shfl_xor(t, 16, 64);
        t += __shfl_xor(t, 32, 64);
        if (h == 0) part[w*16 + nl] = t;
    }
    __syncthreads();
    if (tid < 16){
        float zz = part[tid] + part[16 + tid] + b4[0];
        out[st*16 + tid] = 1.f/(1.f + __expf(-zz));
    }
}

extern "C" void kernel_launch(void* const* d_in, const int* in_sizes, int n_in,
                              void* d_out, int out_size, void* d_ws, size_t ws_size,
                              hipStream_t stream)
{
    (void)in_sizes; (void)n_in; (void)ws_size; (void)out_size;
    const int*   x   = (const int*)d_in[0];
    const float* emb = (const float*)d_in[1];
    u16* ws = (u16*)d_ws;

    swz_kernel<<<(NSWZ+255)/256, 256, 0, stream>>>(
        (const float*)d_in[2],  (const float*)d_in[3],  (const float*)d_in[4],  (const float*)d_in[5],
        (const float*)d_in[6],  (const float*)d_in[7],  (const float*)d_in[8],  (const float*)d_in[9],
        (const float*)d_in[10], (const float*)d_in[11], (const float*)d_in[12], (const float*)d_in[13],
        (const float*)d_in[14], (const float*)d_in[16], (const float*)d_in[18], ws);

    attn_kernel<<<NB/4, 256, 0, stream>>>(x, emb, ws);

    mlp_kernel<<<NB/16, 256, 0, stream>>>(
        (const float*)d_in[15], (const float*)d_in[17], (const float*)d_in[19],
        (const float*)d_in[20], (const float*)d_in[21], ws, (float*)d_out);
}